// Round 2
// baseline (294.077 us; speedup 1.0000x reference)
//
#include <hip/hip_runtime.h>
#include <hip/hip_bf16.h>

// S4D layer: B=16, L=2048, H=512, N=64, fp32.
// Round 7: identical to Round 6 (bench infra flake — resubmit).
//   k_kfused:  time-domain K gen + forward K-FFT in one kernel (512 blocks) -> gKf in ws
//   k_fftconv: reads u directly from (B,L,H) via per-lane strided gathers,
//              scatters y directly to (B,L,H) d_out.
//              XCD partition bid&7 = batch-pair keeps all h-neighbor line sharing
//              (16 h per 64B line) inside one XCD's L2: reads served once from HBM,
//              4B scatter writes merge to full lines in L2.
// FFT math is bit-identical to Round 5 (absmax should be unchanged).
// ws: gKf 16.8 MB only.

#define BSZ 16
#define LSEQ 2048
#define HCH 512
#define NST 64
#define NF 4096

// complex i -> word offset (pad 2 words every 16 complex)
__device__ __forceinline__ int WD(int i) { return 2 * i + ((i >> 4) << 1); }

__device__ __forceinline__ float2 cadd(float2 a, float2 b) { return make_float2(a.x + b.x, a.y + b.y); }
__device__ __forceinline__ float2 csub(float2 a, float2 b) { return make_float2(a.x - b.x, a.y - b.y); }
__device__ __forceinline__ float2 cmul(float2 a, float c, float s) {
    return make_float2(a.x * c - a.y * s, a.x * s + a.y * c);
}
__device__ __forceinline__ float2 cmul2(float2 a, float2 b) {
    return make_float2(a.x * b.x - a.y * b.y, a.x * b.y + a.y * b.x);
}

__device__ __forceinline__ void sincos_red(float a, float* s, float* c) {
    double ad = (double)a;
    double q = rint(ad * 0.15915494309189535);
    float r = (float)(ad - q * 6.283185307179586);
    __sincosf(r, s, c);
}

template <bool INV>
__device__ __forceinline__ void dft8_tail(float2 t0, float2 t1, float2 t2, float2 t3,
                                          float2 t4, float2 t5, float2 t6, float2 t7,
                                          float2& A0, float2& A1, float2& A2, float2& A3,
                                          float2& A4, float2& A5, float2& A6, float2& A7)
{
    const float S = 0.70710678118654752f;
    float2 u0 = cadd(t0, t2), u2 = csub(t0, t2);
    float2 u1 = cadd(t1, t3), u3 = csub(t1, t3);
    A0 = cadd(u0, u1); A4 = csub(u0, u1);
    if constexpr (!INV) {
        A2 = make_float2(u2.x + u3.y, u2.y - u3.x);
        A6 = make_float2(u2.x - u3.y, u2.y + u3.x);
    } else {
        A2 = make_float2(u2.x - u3.y, u2.y + u3.x);
        A6 = make_float2(u2.x + u3.y, u2.y - u3.x);
    }
    float2 b0 = t4, b1, b2, b3;
    if constexpr (!INV) {
        b1 = make_float2(S * (t5.x + t5.y), S * (t5.y - t5.x));
        b2 = make_float2(t6.y, -t6.x);
        b3 = make_float2(S * (t7.y - t7.x), -S * (t7.x + t7.y));
    } else {
        b1 = make_float2(S * (t5.x - t5.y), S * (t5.y + t5.x));
        b2 = make_float2(-t6.y, t6.x);
        b3 = make_float2(-S * (t7.x + t7.y), S * (t7.x - t7.y));
    }
    float2 v0 = cadd(b0, b2), v2 = csub(b0, b2);
    float2 v1 = cadd(b1, b3), v3 = csub(b1, b3);
    A1 = cadd(v0, v1); A5 = csub(v0, v1);
    if constexpr (!INV) {
        A3 = make_float2(v2.x + v3.y, v2.y - v3.x);
        A7 = make_float2(v2.x - v3.y, v2.y + v3.x);
    } else {
        A3 = make_float2(v2.x - v3.y, v2.y + v3.x);
        A7 = make_float2(v2.x + v3.y, v2.y - v3.x);
    }
}

// One radix-8 stage; NT threads, 4096/8/NT butterflies per thread.
template <int SIDX, bool INV, bool HALF, int NT>
__device__ __forceinline__ void fft8_stage(float* z, int t)
{
    constexpr int lgQ = 9 - 3 * SIDX;
    constexpr int Q = 1 << lgQ;
    constexpr int ITERS = 512 / NT;
    const float asc = -1.5339807878856412e-3f * (float)(1 << (3 * SIDX));
#pragma unroll
    for (int it = 0; it < ITERS; ++it) {
        const int bb = t + NT * it;
        const int j = bb & (Q - 1);
        const int base = ((bb >> lgQ) << (lgQ + 3)) + j;
        float s1, c1;
        __sincosf(asc * (float)j, &s1, &c1);
        if constexpr (INV) s1 = -s1;
        const float c2 = c1 * c1 - s1 * s1, s2 = 2.f * c1 * s1;
        const float c3 = c1 * c2 - s1 * s2, s3 = c1 * s2 + s1 * c2;
        const float c4 = c2 * c2 - s2 * s2, s4 = 2.f * c2 * s2;
        const float c5 = c2 * c3 - s2 * s3, s5 = c2 * s3 + s2 * c3;
        const float c6 = c3 * c3 - s3 * s3, s6 = 2.f * c3 * s3;
        const float c7 = c3 * c4 - s3 * s4, s7 = c3 * s4 + s3 * c4;
        float2 a0 = *(float2*)&z[WD(base + 0 * Q)];
        float2 a1 = *(float2*)&z[WD(base + 1 * Q)];
        float2 a2 = *(float2*)&z[WD(base + 2 * Q)];
        float2 a3 = *(float2*)&z[WD(base + 3 * Q)];
        float2 a4, a5, a6, a7;
        if constexpr (!(HALF && !INV)) {
            a4 = *(float2*)&z[WD(base + 4 * Q)];
            a5 = *(float2*)&z[WD(base + 5 * Q)];
            a6 = *(float2*)&z[WD(base + 6 * Q)];
            a7 = *(float2*)&z[WD(base + 7 * Q)];
        }
        if constexpr (INV) {
            a1 = cmul(a1, c1, s1); a2 = cmul(a2, c2, s2); a3 = cmul(a3, c3, s3);
            a4 = cmul(a4, c4, s4); a5 = cmul(a5, c5, s5); a6 = cmul(a6, c6, s6);
            a7 = cmul(a7, c7, s7);
        }
        float2 t0, t1, t2, t3, t4, t5, t6, t7;
        if constexpr (HALF && !INV) {
            t0 = a0; t4 = a0; t1 = a1; t5 = a1; t2 = a2; t6 = a2; t3 = a3; t7 = a3;
        } else {
            t0 = cadd(a0, a4); t4 = csub(a0, a4);
            t1 = cadd(a1, a5); t5 = csub(a1, a5);
            t2 = cadd(a2, a6); t6 = csub(a2, a6);
            t3 = cadd(a3, a7); t7 = csub(a3, a7);
        }
        float2 A0, A1, A2, A3, A4, A5, A6, A7;
        dft8_tail<INV>(t0, t1, t2, t3, t4, t5, t6, t7, A0, A1, A2, A3, A4, A5, A6, A7);
        if constexpr (!INV) {
            A1 = cmul(A1, c1, s1); A2 = cmul(A2, c2, s2); A3 = cmul(A3, c3, s3);
            A4 = cmul(A4, c4, s4); A5 = cmul(A5, c5, s5); A6 = cmul(A6, c6, s6);
            A7 = cmul(A7, c7, s7);
        }
        *(float2*)&z[WD(base + 0 * Q)] = A0;
        *(float2*)&z[WD(base + 1 * Q)] = A1;
        *(float2*)&z[WD(base + 2 * Q)] = A2;
        *(float2*)&z[WD(base + 3 * Q)] = A3;
        if constexpr (!(HALF && INV)) {
            *(float2*)&z[WD(base + 4 * Q)] = A4;
            *(float2*)&z[WD(base + 5 * Q)] = A5;
            *(float2*)&z[WD(base + 6 * Q)] = A6;
            *(float2*)&z[WD(base + 7 * Q)] = A7;
        }
    }
}

// fused: fwd stage3 (Q=1) + pointwise *Kf + inv stage3, in registers
template <int NT>
__device__ __forceinline__ void mid_stage(float* z, const float2* __restrict__ kf, int t)
{
    constexpr int ITERS = 512 / NT;
#pragma unroll
    for (int it = 0; it < ITERS; ++it) {
        const int bb = t + NT * it;
        const int base = bb * 8;
        float2 a[8];
#pragma unroll
        for (int r = 0; r < 8; ++r) a[r] = *(float2*)&z[WD(base + r)];
        float2 t0 = cadd(a[0], a[4]), t4 = csub(a[0], a[4]);
        float2 t1 = cadd(a[1], a[5]), t5 = csub(a[1], a[5]);
        float2 t2 = cadd(a[2], a[6]), t6 = csub(a[2], a[6]);
        float2 t3 = cadd(a[3], a[7]), t7 = csub(a[3], a[7]);
        float2 A0, A1, A2, A3, A4, A5, A6, A7;
        dft8_tail<false>(t0, t1, t2, t3, t4, t5, t6, t7, A0, A1, A2, A3, A4, A5, A6, A7);
        const float2* kp = kf + base;
        A0 = cmul2(A0, kp[0]); A1 = cmul2(A1, kp[1]);
        A2 = cmul2(A2, kp[2]); A3 = cmul2(A3, kp[3]);
        A4 = cmul2(A4, kp[4]); A5 = cmul2(A5, kp[5]);
        A6 = cmul2(A6, kp[6]); A7 = cmul2(A7, kp[7]);
        t0 = cadd(A0, A4); t4 = csub(A0, A4);
        t1 = cadd(A1, A5); t5 = csub(A1, A5);
        t2 = cadd(A2, A6); t6 = csub(A2, A6);
        t3 = cadd(A3, A7); t7 = csub(A3, A7);
        float2 X0, X1, X2, X3, X4, X5, X6, X7;
        dft8_tail<true>(t0, t1, t2, t3, t4, t5, t6, t7, X0, X1, X2, X3, X4, X5, X6, X7);
        *(float2*)&z[WD(base + 0)] = X0;
        *(float2*)&z[WD(base + 1)] = X1;
        *(float2*)&z[WD(base + 2)] = X2;
        *(float2*)&z[WD(base + 3)] = X3;
        *(float2*)&z[WD(base + 4)] = X4;
        *(float2*)&z[WD(base + 5)] = X5;
        *(float2*)&z[WD(base + 6)] = X6;
        *(float2*)&z[WD(base + 7)] = X7;
    }
}

// ------------------- fused: time-domain K gen + forward K-FFT -------------
// 512 blocks (one per h), 512 threads. l-per-thread assignment matches old
// k_kgen exactly (l0 = 4t), so K is bit-identical; FFT stages identical.
__global__ __launch_bounds__(512) void k_kfused(const float* __restrict__ lam_r,
                                                const float* __restrict__ lam_i,
                                                const float* __restrict__ Br,
                                                const float* __restrict__ Bi,
                                                const float* __restrict__ Cr,
                                                const float* __restrict__ Ci,
                                                const float* __restrict__ log_dt,
                                                float* __restrict__ gKf)  // [H][4096] float2
{
    const int h = blockIdx.x;
    const int t = threadIdx.x;  // 512
    __shared__ float z[8704];
    __shared__ float sWr[NST], sWi[NST], sAr[NST], sAi[NST], sDr[NST], sDi[NST];

    if (t < NST) {
        const int n = t;
        float lr = lam_r[n], li = lam_i[n];
        float dt = __expf(log_dt[h]);
        float dar = dt * lr;
        float dai = dt * li;
        float e = __expf(dar);
        float sn, cs; sincos_red(dai, &sn, &cs);
        float Ar = e * cs, Ai = e * sn;
        float nr = Ar - 1.0f, ni = Ai;
        float br = Br[h * NST + n], bi = Bi[h * NST + n];
        float tr = br * nr - bi * ni;
        float ti = br * ni + bi * nr;
        float dr = lr + 1e-8f, di = li;
        float den = dr * dr + di * di;
        float bbr = (tr * dr + ti * di) / den;
        float bbi = (ti * dr - tr * di) / den;
        float cr = Cr[h * NST + n], ci = Ci[h * NST + n];
        sWr[n] = cr * bbr - ci * bbi;
        sWi[n] = cr * bbi + ci * bbr;
        sAr[n] = Ar; sAi[n] = Ai;
        sDr[n] = dar; sDi[n] = dai;
    }
    __syncthreads();

    const int l0 = 4 * t;
    float acc[4] = {0.f, 0.f, 0.f, 0.f};
    const float fl0 = (float)l0;
    for (int n = 0; n < NST; ++n) {
        float dar = sDr[n], dai = sDi[n];
        float ang = dai * fl0;
        float sn, cs; sincos_red(ang, &sn, &cs);
        float e = __expf(dar * fl0);
        float pr = e * cs, pi = e * sn;
        float Ar = sAr[n], Ai = sAi[n];
        float wr = sWr[n], wi = sWi[n];
#pragma unroll
        for (int k = 0; k < 4; ++k) {
            acc[k] += wr * pr - wi * pi;
            float npr = pr * Ar - pi * Ai;
            pi = pr * Ai + pi * Ar;
            pr = npr;
        }
    }
    *(float2*)&z[WD(l0 + 0)] = make_float2(acc[0], 0.f);
    *(float2*)&z[WD(l0 + 1)] = make_float2(acc[1], 0.f);
    *(float2*)&z[WD(l0 + 2)] = make_float2(acc[2], 0.f);
    *(float2*)&z[WD(l0 + 3)] = make_float2(acc[3], 0.f);
    __syncthreads();

    fft8_stage<0, false, true , 512>(z, t); __syncthreads();
    fft8_stage<1, false, false, 512>(z, t); __syncthreads();
    fft8_stage<2, false, false, 512>(z, t); __syncthreads();
    fft8_stage<3, false, false, 512>(z, t); __syncthreads();

    float2* outp = (float2*)gKf + (size_t)h * NF;
#pragma unroll
    for (int i = 0; i < 8; ++i) {
        int idx = t + 512 * i;
        outp[idx] = *(float2*)&z[WD(idx)];
    }
}

// --------------------------------------- FFT convolve, gather/scatter ----
// 4096 blocks: bp = bid&7 (batch pair), h = bid>>3.
// XCD partition: all 16 h-neighbor blocks sharing a 64B input/output line
// land on the same XCD under both round-robin (bid%8=xcd) and chunked
// dispatch -> line fetched from HBM once, 4B writes merge in L2.
__global__ __launch_bounds__(512, 4) void k_fftconv(const float* __restrict__ u,   // (B,L,H)
                                                    const float* __restrict__ gKf, // [H][4096] float2
                                                    const float* __restrict__ gD,
                                                    float* __restrict__ y)         // (B,L,H)
{
    const int bid = blockIdx.x;        // 4096
    const int bp = bid & 7;            // batch pair: (bp, bp+8) share filter
    const int h  = bid >> 3;           // 0..511
    const int t = threadIdx.x;         // 512
    __shared__ float z[8704];

    const size_t base0 = ((size_t)bp * LSEQ) * HCH + h;
    const size_t base1 = ((size_t)(bp + 8) * LSEQ) * HCH + h;
    const int l0 = 4 * t;

    float u0k[4], u1k[4];
#pragma unroll
    for (int k = 0; k < 4; ++k) {
        u0k[k] = u[base0 + (size_t)(l0 + k) * HCH];
        u1k[k] = u[base1 + (size_t)(l0 + k) * HCH];
    }
#pragma unroll
    for (int k = 0; k < 4; ++k)
        *(float2*)&z[WD(l0 + k)] = make_float2(u0k[k], u1k[k]);
    __syncthreads();

    fft8_stage<0, false, true , 512>(z, t); __syncthreads();
    fft8_stage<1, false, false, 512>(z, t); __syncthreads();
    fft8_stage<2, false, false, 512>(z, t); __syncthreads();
    mid_stage<512>(z, (const float2*)gKf + (size_t)h * NF, t); __syncthreads();
    fft8_stage<2, true, false, 512>(z, t); __syncthreads();
    fft8_stage<1, true, false, 512>(z, t); __syncthreads();
    fft8_stage<0, true, true , 512>(z, t); __syncthreads();

    const float sc = 1.0f / 4096.0f;
    const float Dh = gD[h];
#pragma unroll
    for (int k = 0; k < 4; ++k) {
        float2 zz = *(float2*)&z[WD(l0 + k)];
        y[base0 + (size_t)(l0 + k) * HCH] = zz.x * sc + Dh * u0k[k];
        y[base1 + (size_t)(l0 + k) * HCH] = zz.y * sc + Dh * u1k[k];
    }
}

// ----------------------------------------------------------------- launch ---
extern "C" void kernel_launch(void* const* d_in, const int* in_sizes, int n_in,
                              void* d_out, int out_size, void* d_ws, size_t ws_size,
                              hipStream_t stream)
{
    const float* u      = (const float*)d_in[0];
    const float* lam_r  = (const float*)d_in[1];
    const float* lam_i  = (const float*)d_in[2];
    const float* Br     = (const float*)d_in[3];
    const float* Bi     = (const float*)d_in[4];
    const float* Cr     = (const float*)d_in[5];
    const float* Ci     = (const float*)d_in[6];
    const float* log_dt = (const float*)d_in[7];
    const float* Dv     = (const float*)d_in[8];

    float* gKf = (float*)d_ws;   // 16.8 MB

    k_kfused<<<HCH, 512, 0, stream>>>(lam_r, lam_i, Br, Bi, Cr, Ci, log_dt, gKf);
    k_fftconv<<<BSZ / 2 * HCH, 512, 0, stream>>>(u, gKf, Dv, (float*)d_out);
}

// Round 3
// 221.243 us; speedup vs baseline: 1.3292x; 1.3292x over previous
//
#include <hip/hip_runtime.h>
#include <hip/hip_bf16.h>

// S4D layer: B=16, L=2048, H=512, H, N=64, fp32.
// Round 8: revert to proven R5 pipeline (231.8 us), consolidated:
//   k_front:   hetero grid. blocks 0..511 (F): K-gen + K-FFT (R7-proven body)
//              -> Kf in d_out scratch. blocks 512..4607 (T): u (B,L,H) -> gut
//              (B,H,L) 64x64 tile transpose (R5-proven body). Overlaps
//              transcendental-heavy F with BW-bound T.
//   k_fftconv: R5 verbatim (LDS-fed, coalesced, 70.6 us / VALU 71% proven).
//   k_transpose_bwd: R5 verbatim. Overwrites d_out (Kf dead by then).
// ws: gut 67.1 MB only.

#define BSZ 16
#define LSEQ 2048
#define HCH 512
#define NST 64
#define NF 4096

// complex i -> word offset (pad 2 words every 16 complex)
__device__ __forceinline__ int WD(int i) { return 2 * i + ((i >> 4) << 1); }

__device__ __forceinline__ float2 cadd(float2 a, float2 b) { return make_float2(a.x + b.x, a.y + b.y); }
__device__ __forceinline__ float2 csub(float2 a, float2 b) { return make_float2(a.x - b.x, a.y - b.y); }
__device__ __forceinline__ float2 cmul(float2 a, float c, float s) {
    return make_float2(a.x * c - a.y * s, a.x * s + a.y * c);
}
__device__ __forceinline__ float2 cmul2(float2 a, float2 b) {
    return make_float2(a.x * b.x - a.y * b.y, a.x * b.y + a.y * b.x);
}

__device__ __forceinline__ void sincos_red(float a, float* s, float* c) {
    double ad = (double)a;
    double q = rint(ad * 0.15915494309189535);
    float r = (float)(ad - q * 6.283185307179586);
    __sincosf(r, s, c);
}

template <bool INV>
__device__ __forceinline__ void dft8_tail(float2 t0, float2 t1, float2 t2, float2 t3,
                                          float2 t4, float2 t5, float2 t6, float2 t7,
                                          float2& A0, float2& A1, float2& A2, float2& A3,
                                          float2& A4, float2& A5, float2& A6, float2& A7)
{
    const float S = 0.70710678118654752f;
    float2 u0 = cadd(t0, t2), u2 = csub(t0, t2);
    float2 u1 = cadd(t1, t3), u3 = csub(t1, t3);
    A0 = cadd(u0, u1); A4 = csub(u0, u1);
    if constexpr (!INV) {
        A2 = make_float2(u2.x + u3.y, u2.y - u3.x);
        A6 = make_float2(u2.x - u3.y, u2.y + u3.x);
    } else {
        A2 = make_float2(u2.x - u3.y, u2.y + u3.x);
        A6 = make_float2(u2.x + u3.y, u2.y - u3.x);
    }
    float2 b0 = t4, b1, b2, b3;
    if constexpr (!INV) {
        b1 = make_float2(S * (t5.x + t5.y), S * (t5.y - t5.x));
        b2 = make_float2(t6.y, -t6.x);
        b3 = make_float2(S * (t7.y - t7.x), -S * (t7.x + t7.y));
    } else {
        b1 = make_float2(S * (t5.x - t5.y), S * (t5.y + t5.x));
        b2 = make_float2(-t6.y, t6.x);
        b3 = make_float2(-S * (t7.x + t7.y), S * (t7.x - t7.y));
    }
    float2 v0 = cadd(b0, b2), v2 = csub(b0, b2);
    float2 v1 = cadd(b1, b3), v3 = csub(b1, b3);
    A1 = cadd(v0, v1); A5 = csub(v0, v1);
    if constexpr (!INV) {
        A3 = make_float2(v2.x + v3.y, v2.y - v3.x);
        A7 = make_float2(v2.x - v3.y, v2.y + v3.x);
    } else {
        A3 = make_float2(v2.x - v3.y, v2.y + v3.x);
        A7 = make_float2(v2.x + v3.y, v2.y - v3.x);
    }
}

// One radix-8 stage; NT threads, 4096/8/NT butterflies per thread.
template <int SIDX, bool INV, bool HALF, int NT>
__device__ __forceinline__ void fft8_stage(float* z, int t)
{
    constexpr int lgQ = 9 - 3 * SIDX;
    constexpr int Q = 1 << lgQ;
    constexpr int ITERS = 512 / NT;
    const float asc = -1.5339807878856412e-3f * (float)(1 << (3 * SIDX));
#pragma unroll
    for (int it = 0; it < ITERS; ++it) {
        const int bb = t + NT * it;
        const int j = bb & (Q - 1);
        const int base = ((bb >> lgQ) << (lgQ + 3)) + j;
        float s1, c1;
        __sincosf(asc * (float)j, &s1, &c1);
        if constexpr (INV) s1 = -s1;
        const float c2 = c1 * c1 - s1 * s1, s2 = 2.f * c1 * s1;
        const float c3 = c1 * c2 - s1 * s2, s3 = c1 * s2 + s1 * c2;
        const float c4 = c2 * c2 - s2 * s2, s4 = 2.f * c2 * s2;
        const float c5 = c2 * c3 - s2 * s3, s5 = c2 * s3 + s2 * c3;
        const float c6 = c3 * c3 - s3 * s3, s6 = 2.f * c3 * s3;
        const float c7 = c3 * c4 - s3 * s4, s7 = c3 * s4 + s3 * c4;
        float2 a0 = *(float2*)&z[WD(base + 0 * Q)];
        float2 a1 = *(float2*)&z[WD(base + 1 * Q)];
        float2 a2 = *(float2*)&z[WD(base + 2 * Q)];
        float2 a3 = *(float2*)&z[WD(base + 3 * Q)];
        float2 a4, a5, a6, a7;
        if constexpr (!(HALF && !INV)) {
            a4 = *(float2*)&z[WD(base + 4 * Q)];
            a5 = *(float2*)&z[WD(base + 5 * Q)];
            a6 = *(float2*)&z[WD(base + 6 * Q)];
            a7 = *(float2*)&z[WD(base + 7 * Q)];
        }
        if constexpr (INV) {
            a1 = cmul(a1, c1, s1); a2 = cmul(a2, c2, s2); a3 = cmul(a3, c3, s3);
            a4 = cmul(a4, c4, s4); a5 = cmul(a5, c5, s5); a6 = cmul(a6, c6, s6);
            a7 = cmul(a7, c7, s7);
        }
        float2 t0, t1, t2, t3, t4, t5, t6, t7;
        if constexpr (HALF && !INV) {
            t0 = a0; t4 = a0; t1 = a1; t5 = a1; t2 = a2; t6 = a2; t3 = a3; t7 = a3;
        } else {
            t0 = cadd(a0, a4); t4 = csub(a0, a4);
            t1 = cadd(a1, a5); t5 = csub(a1, a5);
            t2 = cadd(a2, a6); t6 = csub(a2, a6);
            t3 = cadd(a3, a7); t7 = csub(a3, a7);
        }
        float2 A0, A1, A2, A3, A4, A5, A6, A7;
        dft8_tail<INV>(t0, t1, t2, t3, t4, t5, t6, t7, A0, A1, A2, A3, A4, A5, A6, A7);
        if constexpr (!INV) {
            A1 = cmul(A1, c1, s1); A2 = cmul(A2, c2, s2); A3 = cmul(A3, c3, s3);
            A4 = cmul(A4, c4, s4); A5 = cmul(A5, c5, s5); A6 = cmul(A6, c6, s6);
            A7 = cmul(A7, c7, s7);
        }
        *(float2*)&z[WD(base + 0 * Q)] = A0;
        *(float2*)&z[WD(base + 1 * Q)] = A1;
        *(float2*)&z[WD(base + 2 * Q)] = A2;
        *(float2*)&z[WD(base + 3 * Q)] = A3;
        if constexpr (!(HALF && INV)) {
            *(float2*)&z[WD(base + 4 * Q)] = A4;
            *(float2*)&z[WD(base + 5 * Q)] = A5;
            *(float2*)&z[WD(base + 6 * Q)] = A6;
            *(float2*)&z[WD(base + 7 * Q)] = A7;
        }
    }
}

// fused: fwd stage3 (Q=1) + pointwise *Kf + inv stage3, in registers
template <int NT>
__device__ __forceinline__ void mid_stage(float* z, const float2* __restrict__ kf, int t)
{
    constexpr int ITERS = 512 / NT;
#pragma unroll
    for (int it = 0; it < ITERS; ++it) {
        const int bb = t + NT * it;
        const int base = bb * 8;
        float2 a[8];
#pragma unroll
        for (int r = 0; r < 8; ++r) a[r] = *(float2*)&z[WD(base + r)];
        float2 t0 = cadd(a[0], a[4]), t4 = csub(a[0], a[4]);
        float2 t1 = cadd(a[1], a[5]), t5 = csub(a[1], a[5]);
        float2 t2 = cadd(a[2], a[6]), t6 = csub(a[2], a[6]);
        float2 t3 = cadd(a[3], a[7]), t7 = csub(a[3], a[7]);
        float2 A0, A1, A2, A3, A4, A5, A6, A7;
        dft8_tail<false>(t0, t1, t2, t3, t4, t5, t6, t7, A0, A1, A2, A3, A4, A5, A6, A7);
        const float2* kp = kf + base;
        A0 = cmul2(A0, kp[0]); A1 = cmul2(A1, kp[1]);
        A2 = cmul2(A2, kp[2]); A3 = cmul2(A3, kp[3]);
        A4 = cmul2(A4, kp[4]); A5 = cmul2(A5, kp[5]);
        A6 = cmul2(A6, kp[6]); A7 = cmul2(A7, kp[7]);
        t0 = cadd(A0, A4); t4 = csub(A0, A4);
        t1 = cadd(A1, A5); t5 = csub(A1, A5);
        t2 = cadd(A2, A6); t6 = csub(A2, A6);
        t3 = cadd(A3, A7); t7 = csub(A3, A7);
        float2 X0, X1, X2, X3, X4, X5, X6, X7;
        dft8_tail<true>(t0, t1, t2, t3, t4, t5, t6, t7, X0, X1, X2, X3, X4, X5, X6, X7);
        *(float2*)&z[WD(base + 0)] = X0;
        *(float2*)&z[WD(base + 1)] = X1;
        *(float2*)&z[WD(base + 2)] = X2;
        *(float2*)&z[WD(base + 3)] = X3;
        *(float2*)&z[WD(base + 4)] = X4;
        *(float2*)&z[WD(base + 5)] = X5;
        *(float2*)&z[WD(base + 6)] = X6;
        *(float2*)&z[WD(base + 7)] = X7;
    }
}

// -------- hetero front: [F: 512 blocks] K-gen + K-FFT  ||  [T: 4096] u->gut
__global__ __launch_bounds__(512) void k_front(const float* __restrict__ lam_r,
                                               const float* __restrict__ lam_i,
                                               const float* __restrict__ Br,
                                               const float* __restrict__ Bi,
                                               const float* __restrict__ Cr,
                                               const float* __restrict__ Ci,
                                               const float* __restrict__ log_dt,
                                               float* __restrict__ gKf,        // [H][4096] float2
                                               const float* __restrict__ u,    // (B,L,H)
                                               float* __restrict__ gut)        // (B,H,L)
{
    const int bid = blockIdx.x;
    const int t = threadIdx.x;  // 512
    __shared__ float lds[8704];
    __shared__ float sWr[NST], sWi[NST], sAr[NST], sAi[NST], sDr[NST], sDi[NST];

    if (bid < HCH) {
        // ---- role F: time-domain K gen + forward FFT of K row ----
        const int h = bid;
        if (t < NST) {
            const int n = t;
            float lr = lam_r[n], li = lam_i[n];
            float dt = __expf(log_dt[h]);
            float dar = dt * lr;
            float dai = dt * li;
            float e = __expf(dar);
            float sn, cs; sincos_red(dai, &sn, &cs);
            float Ar = e * cs, Ai = e * sn;
            float nr = Ar - 1.0f, ni = Ai;
            float br = Br[h * NST + n], bi = Bi[h * NST + n];
            float tr = br * nr - bi * ni;
            float ti = br * ni + bi * nr;
            float dr = lr + 1e-8f, di = li;
            float den = dr * dr + di * di;
            float bbr = (tr * dr + ti * di) / den;
            float bbi = (ti * dr - tr * di) / den;
            float cr = Cr[h * NST + n], ci = Ci[h * NST + n];
            sWr[n] = cr * bbr - ci * bbi;
            sWi[n] = cr * bbi + ci * bbr;
            sAr[n] = Ar; sAi[n] = Ai;
            sDr[n] = dar; sDi[n] = dai;
        }
        __syncthreads();

        const int l0 = 4 * t;
        float acc[4] = {0.f, 0.f, 0.f, 0.f};
        const float fl0 = (float)l0;
        for (int n = 0; n < NST; ++n) {
            float dar = sDr[n], dai = sDi[n];
            float ang = dai * fl0;
            float sn, cs; sincos_red(ang, &sn, &cs);
            float e = __expf(dar * fl0);
            float pr = e * cs, pi = e * sn;
            float Ar = sAr[n], Ai = sAi[n];
            float wr = sWr[n], wi = sWi[n];
#pragma unroll
            for (int k = 0; k < 4; ++k) {
                acc[k] += wr * pr - wi * pi;
                float npr = pr * Ar - pi * Ai;
                pi = pr * Ai + pi * Ar;
                pr = npr;
            }
        }
        *(float2*)&lds[WD(l0 + 0)] = make_float2(acc[0], 0.f);
        *(float2*)&lds[WD(l0 + 1)] = make_float2(acc[1], 0.f);
        *(float2*)&lds[WD(l0 + 2)] = make_float2(acc[2], 0.f);
        *(float2*)&lds[WD(l0 + 3)] = make_float2(acc[3], 0.f);
        __syncthreads();

        fft8_stage<0, false, true , 512>(lds, t); __syncthreads();
        fft8_stage<1, false, false, 512>(lds, t); __syncthreads();
        fft8_stage<2, false, false, 512>(lds, t); __syncthreads();
        fft8_stage<3, false, false, 512>(lds, t); __syncthreads();

        float2* outp = (float2*)gKf + (size_t)h * NF;
#pragma unroll
        for (int i = 0; i < 8; ++i) {
            int idx = t + 512 * i;
            outp[idx] = *(float2*)&lds[WD(idx)];
        }
    } else {
        // ---- role T: 64x64 transpose tile, 512 threads (R5-proven) ----
        float (*tile)[65] = (float (*)[65])lds;
        const int tid2 = bid - HCH;
        const int b  = tid2 >> 8;
        const int ht = ((tid2 >> 5) & 7) * 64;
        const int lt = (tid2 & 31) * 64;
        const int tx = t & 15;   // float4 column
        const int ty = t >> 4;   // 0..31
        const float* inb = u + (size_t)b * LSEQ * HCH;
        float* outb = gut + (size_t)b * HCH * LSEQ;
#pragma unroll
        for (int i = 0; i < 2; ++i) {
            int r = ty + 32 * i;
            float4 v = *(const float4*)&inb[(size_t)(lt + r) * HCH + ht + 4 * tx];
            tile[r][4 * tx + 0] = v.x;
            tile[r][4 * tx + 1] = v.y;
            tile[r][4 * tx + 2] = v.z;
            tile[r][4 * tx + 3] = v.w;
        }
        __syncthreads();
#pragma unroll
        for (int i = 0; i < 2; ++i) {
            int rp = ty + 32 * i;
            float4 o = make_float4(tile[4 * tx + 0][rp], tile[4 * tx + 1][rp],
                                   tile[4 * tx + 2][rp], tile[4 * tx + 3][rp]);
            *(float4*)&outb[(size_t)(ht + rp) * LSEQ + lt + 4 * tx] = o;
        }
    }
}

// -------------------------------------------------------- bwd transpose ---
__global__ __launch_bounds__(256) void k_transpose_bwd(const float* __restrict__ in,  // (B,H,L)
                                                       float* __restrict__ out)       // (B,L,H)
{
    __shared__ float tile[64][65];
    const int b  = blockIdx.z;
    const int lt = blockIdx.x * 64;
    const int ht = blockIdx.y * 64;
    const int tx = threadIdx.x;
    const int ty = threadIdx.y;
    const float* inb = in + (size_t)b * HCH * LSEQ;
    float* outb = out + (size_t)b * LSEQ * HCH;
#pragma unroll
    for (int i = 0; i < 4; ++i) {
        int r = ty + 16 * i;
        float4 v = *(const float4*)&inb[(size_t)(ht + r) * LSEQ + lt + 4 * tx];
        tile[r][4 * tx + 0] = v.x;
        tile[r][4 * tx + 1] = v.y;
        tile[r][4 * tx + 2] = v.z;
        tile[r][4 * tx + 3] = v.w;
    }
    __syncthreads();
#pragma unroll
    for (int i = 0; i < 4; ++i) {
        int rp = ty + 16 * i;
        float4 o = make_float4(tile[4 * tx + 0][rp], tile[4 * tx + 1][rp],
                               tile[4 * tx + 2][rp], tile[4 * tx + 3][rp]);
        *(float4*)&outb[(size_t)(lt + rp) * HCH + ht + 4 * tx] = o;
    }
}

// ----------------------------------------------------------- FFT convolve ---
__global__ __launch_bounds__(512, 4) void k_fftconv(float* __restrict__ gut,       // [B][H][L]
                                                    const float* __restrict__ gKf, // [H][4096] float2
                                                    const float* __restrict__ gD)
{
    const int bid = blockIdx.x;        // 4096
    const int b = bid >> 9;            // 0..7
    const int h = bid & (HCH - 1);
    const int t = threadIdx.x;         // 512
    __shared__ float z[8704];

    float* row0 = gut + ((size_t)(b * HCH) + h) * LSEQ;
    float* row1 = gut + ((size_t)((b + 8) * HCH) + h) * LSEQ;

    float4 u0k = ((const float4*)row0)[t];
    float4 u1k = ((const float4*)row1)[t];
    {
        int l = 4 * t;
        *(float2*)&z[WD(l + 0)] = make_float2(u0k.x, u1k.x);
        *(float2*)&z[WD(l + 1)] = make_float2(u0k.y, u1k.y);
        *(float2*)&z[WD(l + 2)] = make_float2(u0k.z, u1k.z);
        *(float2*)&z[WD(l + 3)] = make_float2(u0k.w, u1k.w);
    }
    __syncthreads();

    fft8_stage<0, false, true , 512>(z, t); __syncthreads();
    fft8_stage<1, false, false, 512>(z, t); __syncthreads();
    fft8_stage<2, false, false, 512>(z, t); __syncthreads();
    mid_stage<512>(z, (const float2*)gKf + (size_t)h * NF, t); __syncthreads();
    fft8_stage<2, true, false, 512>(z, t); __syncthreads();
    fft8_stage<1, true, false, 512>(z, t); __syncthreads();
    fft8_stage<0, true, true , 512>(z, t); __syncthreads();

    const float sc = 1.0f / 4096.0f;
    const float Dh = gD[h];
    {
        int l = 4 * t;
        float2 z0 = *(float2*)&z[WD(l + 0)];
        float2 z1 = *(float2*)&z[WD(l + 1)];
        float2 z2 = *(float2*)&z[WD(l + 2)];
        float2 z3 = *(float2*)&z[WD(l + 3)];
        float4 o0 = make_float4(z0.x * sc + Dh * u0k.x, z1.x * sc + Dh * u0k.y,
                                z2.x * sc + Dh * u0k.z, z3.x * sc + Dh * u0k.w);
        float4 o1 = make_float4(z0.y * sc + Dh * u1k.x, z1.y * sc + Dh * u1k.y,
                                z2.y * sc + Dh * u1k.z, z3.y * sc + Dh * u1k.w);
        ((float4*)row0)[t] = o0;
        ((float4*)row1)[t] = o1;
    }
}

// ----------------------------------------------------------------- launch ---
extern "C" void kernel_launch(void* const* d_in, const int* in_sizes, int n_in,
                              void* d_out, int out_size, void* d_ws, size_t ws_size,
                              hipStream_t stream)
{
    const float* u      = (const float*)d_in[0];
    const float* lam_r  = (const float*)d_in[1];
    const float* lam_i  = (const float*)d_in[2];
    const float* Br     = (const float*)d_in[3];
    const float* Bi     = (const float*)d_in[4];
    const float* Cr     = (const float*)d_in[5];
    const float* Ci     = (const float*)d_in[6];
    const float* log_dt = (const float*)d_in[7];
    const float* Dv     = (const float*)d_in[8];

    float* gut = (float*)d_ws;     // 67.1 MB
    float* gKf = (float*)d_out;    // 16.8 MB scratch until tbwd

    k_front<<<HCH + 4096, 512, 0, stream>>>(lam_r, lam_i, Br, Bi, Cr, Ci, log_dt,
                                            gKf, u, gut);
    k_fftconv<<<BSZ / 2 * HCH, 512, 0, stream>>>(gut, gKf, Dv);
    k_transpose_bwd<<<dim3(LSEQ / 64, HCH / 64, BSZ), dim3(16, 16, 1), 0, stream>>>(gut, (float*)d_out);
}